// Round 4
// baseline (250.814 us; speedup 1.0000x reference)
//
#include <hip/hip_runtime.h>
#include <hip/hip_bf16.h>

// NPairLoss on MI355X (gfx950).
// loss = mean_i [ log( rowsum_i + e ) - pos_sim_i ] + 0.02*||examples||_F
// rowsum_i = sum_j exp(sim_ij), sim = (A/|A|)·(P/|P|)^T ; diag-replacement -> +e.
//
// GEMM: 256x256 tile, BK=32, 8 waves (2Mx4N), THREE LDS buffers (96 KiB),
// counted-vmcnt phase schedule (T3+T4): 2 phases/K-tile, 16 MFMA/phase,
// 1 chunk (16KB) staged per phase, vmcnt(4) at tile boundaries (never 0 in
// steady state), raw s_barrier (no drain). T2 XOR swizzle (both-sides:
// pre-swizzled global_load_lds SOURCE + swizzled ds_read; LDS dest LINEAR —
// rule #21). T5 setprio around MFMA clusters. T1 XCD block swizzle.
//
// global_load_lds HW contract (m104/m108): LDS dest = wave-uniform base +
// lane*16. Each stage instruction covers exactly 64 lanes x 16B = 1024B
// contiguous LDS; per-lane variation lives ONLY in the global source addr.
//
// Ledger: tile kt staged during kt-2 into buf[kt%3]; buf[kt%3] last read at
// kt-1's phases (reads drained by lgkmcnt(0) before B4 boundary barrier);
// boundary vmcnt(4) at end of kt-1 leaves only kt+1's 4 loads in flight
// => tile kt fully resident when kt's reads begin. Race-free.

#define NR 8192
#define DD 512
#define E_CONST 2.71828182845904523536f

typedef __attribute__((ext_vector_type(8))) short bf16x8_t;
typedef __attribute__((ext_vector_type(4))) float f32x4_t;
#define AS1 __attribute__((address_space(1)))
#define AS3 __attribute__((address_space(3)))

__device__ __forceinline__ ushort f2bf(float x) {
    __hip_bfloat16 h = __float2bfloat16(x);
    return *reinterpret_cast<ushort*>(&h);
}

// ---------------- prep: normalize rows -> bf16, pos_sim, norm2, zero accums ---
__global__ __launch_bounds__(128) void prep_kernel(
    const float* __restrict__ ex,
    ushort* __restrict__ Ah, ushort* __restrict__ Ph,
    float* __restrict__ pos_sim, float* __restrict__ norm2,
    float* __restrict__ rowsum, float* __restrict__ part)
{
    const int i = blockIdx.x;
    const int t = threadIdx.x;            // 0..127, 4 floats each
    const float4 a = ((const float4*)(ex + (size_t)i * 1024))[t];
    const float4 p = ((const float4*)(ex + (size_t)i * 1024 + 512))[t];
    float sa  = a.x*a.x + a.y*a.y + a.z*a.z + a.w*a.w;
    float sp  = p.x*p.x + p.y*p.y + p.z*p.z + p.w*p.w;
    float sap = a.x*p.x + a.y*p.y + a.z*p.z + a.w*p.w;
    #pragma unroll
    for (int m = 1; m < 64; m <<= 1) {
        sa  += __shfl_xor(sa,  m, 64);
        sp  += __shfl_xor(sp,  m, 64);
        sap += __shfl_xor(sap, m, 64);
    }
    __shared__ float red[3][2];
    if ((t & 63) == 0) { red[0][t>>6] = sa; red[1][t>>6] = sp; red[2][t>>6] = sap; }
    __syncthreads();
    sa  = red[0][0] + red[0][1];
    sp  = red[1][0] + red[1][1];
    sap = red[2][0] + red[2][1];
    const float inva = rsqrtf(sa);
    const float invp = rsqrtf(sp);
    ushort4 av, pv;
    av.x = f2bf(a.x * inva); av.y = f2bf(a.y * inva);
    av.z = f2bf(a.z * inva); av.w = f2bf(a.w * inva);
    pv.x = f2bf(p.x * invp); pv.y = f2bf(p.y * invp);
    pv.z = f2bf(p.z * invp); pv.w = f2bf(p.w * invp);
    ((ushort4*)(Ah + (size_t)i * DD))[t] = av;
    ((ushort4*)(Ph + (size_t)i * DD))[t] = pv;
    if (t == 0) {
        pos_sim[i] = sap * inva * invp;
        norm2[i]   = sa + sp;
        rowsum[i]  = 0.0f;
        if (i == 0) { part[0] = 0.0f; part[1] = 0.0f; }
    }
}

// ---------------- GEMM 256^2, BK=32, 3-buffer counted-vmcnt schedule ----------
__global__ __launch_bounds__(512, 2) void gemm_kernel(
    const ushort* __restrict__ Ah, const ushort* __restrict__ Ph,
    float* __restrict__ rowsum)
{
    // ls: 3 buffers x (A: 256x32 + B: 256x32) ushorts = 3 x 16384 = 49152 (96 KiB)
    __shared__ ushort ls[49152];
    const int t  = threadIdx.x;           // 0..511
    const int w  = t >> 6;                // wave 0..7
    const int l  = t & 63;
    const int wr = w >> 2, wc = w & 3;    // 2M x 4N wave grid
    const int ll = l & 15, lh = l >> 4;

    // T1: XCD-aware bijective swizzle (nwg=1024, 1024%8==0)
    const int wgid = (blockIdx.x & 7) * 128 + (blockIdx.x >> 3);
    const int m0 = (wgid >> 5) * 256;
    const int n0 = (wgid & 31) * 256;

    f32x4_t acc[8][4];
    #pragma unroll
    for (int i = 0; i < 8; i++)
        #pragma unroll
        for (int j = 0; j < 4; j++)
            acc[i][j] = (f32x4_t){0.f, 0.f, 0.f, 0.f};

    // staging: chunk = one matrix x one K-tile = 256 rows x 64 B = 16 KiB.
    // wave w, instr j: rows w*32+j*16 .. +16 -> LDS bytes [w*2048+j*1024, +1024)
    // LINEAR (lane l at +l*16). lane l -> row r = w*32+j*16+(l>>2), slot l&3.
    // Source pre-swizzle: LDS[r][sl] holds G[r][sl ^ ((r>>1)&3)].
    auto stage = [&](int buf, int kt, const ushort* src, int chunkOff, int rowBase) {
        #pragma unroll
        for (int j = 0; j < 2; ++j) {
            const int r   = w * 32 + j * 16 + (l >> 2);
            const int gsl = (l & 3) ^ ((r >> 1) & 3);
            const char* g = (const char*)src + (size_t)(rowBase + r) * (DD * 2)
                            + kt * 64 + gsl * 16;
            __builtin_amdgcn_global_load_lds(
                (const AS1 void*)g,
                (AS3 void*)((char*)ls + buf * 32768 + chunkOff
                            + w * 2048 + j * 1024 + l * 16),
                16, 0, 0);
        }
    };

    // fragment read swizzle: k-slot lh of row R lives at LDS slot lh ^ ((R>>1)&3),
    // and (R>>1)&3 == (ll>>1)&3 (row bases are 16-aligned).
    const int sA = lh ^ ((ll >> 1) & 3);

    // prologue: stage tiles 0 (buf0) and 1 (buf1); wait tile 0 (tile 1's 4
    // loads may stay in flight), barrier.
    stage(0, 0, Ah, 0,     m0);
    stage(0, 0, Ph, 16384, n0);
    stage(1, 1, Ah, 0,     m0);
    stage(1, 1, Ph, 16384, n0);
    asm volatile("s_waitcnt vmcnt(4)" ::: "memory");
    __builtin_amdgcn_s_barrier();
    __builtin_amdgcn_sched_barrier(0);

    int bufc = 0, bufn = 2;               // current buffer, stage-target buffer
    #pragma unroll 1
    for (int kt = 0; kt < DD / 32; ++kt) {
        const int aB = bufc * 16384;           // ushort index
        const int bB = bufc * 16384 + 8192;

        // ---- phase 0: A frags mi 0-3, all B frags; stage A-chunk of kt+2 ----
        bf16x8_t a0[4], bfv[4];
        #pragma unroll
        for (int mi = 0; mi < 4; ++mi)
            a0[mi] = *(const bf16x8_t*)&ls[aB + (wr * 128 + mi * 16 + ll) * 32 + sA * 8];
        #pragma unroll
        for (int ni = 0; ni < 4; ++ni)
            bfv[ni] = *(const bf16x8_t*)&ls[bB + (wc * 64 + ni * 16 + ll) * 32 + sA * 8];
        if (kt < DD / 32 - 2) stage(bufn, kt + 2, Ah, 0, m0);
        __builtin_amdgcn_s_barrier();
        asm volatile("s_waitcnt lgkmcnt(0)" ::: "memory");
        __builtin_amdgcn_sched_barrier(0);
        __builtin_amdgcn_s_setprio(1);
        #pragma unroll
        for (int mi = 0; mi < 4; ++mi)
            #pragma unroll
            for (int ni = 0; ni < 4; ++ni)
                acc[mi][ni] = __builtin_amdgcn_mfma_f32_16x16x32_bf16(
                    a0[mi], bfv[ni], acc[mi][ni], 0, 0, 0);
        __builtin_amdgcn_s_setprio(0);
        __builtin_amdgcn_s_barrier();

        // ---- phase 1: A frags mi 4-7 (B reused); stage B-chunk of kt+2 ------
        bf16x8_t a1[4];
        #pragma unroll
        for (int mi = 0; mi < 4; ++mi)
            a1[mi] = *(const bf16x8_t*)&ls[aB + (wr * 128 + (mi + 4) * 16 + ll) * 32 + sA * 8];
        if (kt < DD / 32 - 2) stage(bufn, kt + 2, Ph, 16384, n0);
        __builtin_amdgcn_s_barrier();
        asm volatile("s_waitcnt lgkmcnt(0)" ::: "memory");
        __builtin_amdgcn_sched_barrier(0);
        __builtin_amdgcn_s_setprio(1);
        #pragma unroll
        for (int mi = 0; mi < 4; ++mi)
            #pragma unroll
            for (int ni = 0; ni < 4; ++ni)
                acc[mi + 4][ni] = __builtin_amdgcn_mfma_f32_16x16x32_bf16(
                    a1[mi], bfv[ni], acc[mi + 4][ni], 0, 0, 0);
        __builtin_amdgcn_s_setprio(0);

        // ---- K-tile boundary: counted vmcnt (4 = kt+2's loads in flight) ----
        if (kt < DD / 32 - 2) {
            asm volatile("s_waitcnt vmcnt(4)" ::: "memory");
        } else {
            asm volatile("s_waitcnt vmcnt(0)" ::: "memory");
        }
        __builtin_amdgcn_s_barrier();
        __builtin_amdgcn_sched_barrier(0);

        bufc = (bufc == 2) ? 0 : bufc + 1;
        bufn = (bufn == 2) ? 0 : bufn + 1;
    }

    // epilogue: per-row sum of exp over this block's 256 cols -> atomicAdd.
    // C/D: col = n0 + wc*64 + ni*16 + ll ; row = m0 + wr*128 + mi*16 + lh*4 + r
    #pragma unroll
    for (int mi = 0; mi < 8; ++mi) {
        #pragma unroll
        for (int r = 0; r < 4; ++r) {
            float s = __expf(acc[mi][0][r]) + __expf(acc[mi][1][r]) +
                      __expf(acc[mi][2][r]) + __expf(acc[mi][3][r]);
            s += __shfl_xor(s, 1, 64);
            s += __shfl_xor(s, 2, 64);
            s += __shfl_xor(s, 4, 64);
            s += __shfl_xor(s, 8, 64);
            if (ll == 0)
                atomicAdd(&rowsum[m0 + wr * 128 + mi * 16 + lh * 4 + r], s);
        }
    }
}

// ---------------- final reduce (parallel) -------------------------------------
__global__ __launch_bounds__(256) void final1_kernel(
    const float* __restrict__ rowsum, const float* __restrict__ pos_sim,
    const float* __restrict__ norm2, float* __restrict__ part)
{
    const int i = blockIdx.x * 256 + threadIdx.x;   // 32 blocks x 256 = 8192
    float s1 = logf(rowsum[i] + E_CONST) - pos_sim[i];
    float s2 = norm2[i];
    #pragma unroll
    for (int m = 1; m < 64; m <<= 1) {
        s1 += __shfl_xor(s1, m, 64);
        s2 += __shfl_xor(s2, m, 64);
    }
    if ((threadIdx.x & 63) == 0) {
        atomicAdd(&part[0], s1);
        atomicAdd(&part[1], s2);
    }
}

__global__ void final2_kernel(const float* __restrict__ part, float* __restrict__ out)
{
    out[0] = part[0] * (1.0f / NR) + 0.02f * sqrtf(part[1]);
}

extern "C" void kernel_launch(void* const* d_in, const int* in_sizes, int n_in,
                              void* d_out, int out_size, void* d_ws, size_t ws_size,
                              hipStream_t stream) {
    const float* ex = (const float*)d_in[0];
    float* out = (float*)d_out;
    char* ws = (char*)d_ws;
    ushort* Ah     = (ushort*)(ws);                         // 8 MiB
    ushort* Ph     = (ushort*)(ws + 8388608);               // 8 MiB
    float*  possim = (float*)(ws + 16777216);               // 32 KiB
    float*  norm2  = (float*)(ws + 16777216 + 32768);       // 32 KiB
    float*  rowsum = (float*)(ws + 16777216 + 65536);       // 32 KiB
    float*  part   = (float*)(ws + 16777216 + 98304);       // 8 B

    prep_kernel<<<NR, 128, 0, stream>>>(ex, Ah, Ph, possim, norm2, rowsum, part);
    gemm_kernel<<<(NR / 256) * (NR / 256), 512, 0, stream>>>(Ah, Ph, rowsum);
    final1_kernel<<<NR / 256, 256, 0, stream>>>(rowsum, possim, norm2, part);
    final2_kernel<<<1, 1, 0, stream>>>(part, out);
}

// Round 6
// 205.199 us; speedup vs baseline: 1.2223x; 1.2223x over previous
//
#include <hip/hip_runtime.h>
#include <hip/hip_bf16.h>

// NPairLoss on MI355X (gfx950).
// loss = mean_i [ log( rowsum_i + e ) - pos_sim_i ] + 0.02*||examples||_F
// rowsum_i = sum_j exp(sim_ij), sim = (A/|A|)·(P/|P|)^T ; diag-replacement -> +e.
//
// GEMM: 256x256 tile, 8 waves (2Mx4N), 8-phase-style counted-vmcnt schedule:
// ring of 4 BK=32 slices in LDS (128 KiB), per phase { ds_read frags | stage
// ONE chunk (A or B of slice s+3) | vmcnt(8) | 16 MFMA (setprio) | barrier }.
// vmcnt never drains in steady state; tail waits 8 -> 4 -> 0.
// T2 both-sides XOR swizzle (pre-swizzled global source, LINEAR LDS dest per
// global_load_lds HW contract, swizzled ds_read) -> 0 bank conflicts (meas.).
// Block mapping: plain 2D grid (R2-measured 37MB FETCH; do NOT XCD-flatten:
// R4 measured 135MB/3.7x from per-XCD L2 thrash).
//
// Ledger (chunk c: slice=c>>1, matrix=c&1; 2 loads/chunk/wave):
//   prologue: chunks 0..5 (A0,B0,A1,B1,A2,B2), vmcnt(8) => slice0 resident.
//   phase 2s+ph stages chunk 6+2s+ph (ph0: A_{s+3}, ph1: B_{s+3}), s<=12.
//   end-of-phase vmcnt(8): landed >= issued-4 chunks => slice s+1 resident
//   before its reads; tail (no new stages): s=13 -> vmcnt(4), s=14 -> vmcnt(0).
//   WAR: stage A_{s+3} (slot s-1) issues after barrier@ph1(s-1), by which all
//   waves' reads of slice s-1 retired (reads complete before their MFMAs,
//   MFMAs before barrier). Race-free.

#define NR 8192
#define DD 512
#define NSL 16              // K slices of 32
#define E_CONST 2.71828182845904523536f

typedef __attribute__((ext_vector_type(8))) short bf16x8_t;
typedef __attribute__((ext_vector_type(4))) float f32x4_t;
#define AS1 __attribute__((address_space(1)))
#define AS3 __attribute__((address_space(3)))

__device__ __forceinline__ ushort f2bf(float x) {
    __hip_bfloat16 h = __float2bfloat16(x);
    return *reinterpret_cast<ushort*>(&h);
}

// ---------------- prep: normalize rows -> bf16, pos_sim, norm2, zero rowsum --
__global__ __launch_bounds__(128) void prep_kernel(
    const float* __restrict__ ex,
    ushort* __restrict__ Ah, ushort* __restrict__ Ph,
    float* __restrict__ pos_sim, float* __restrict__ norm2,
    float* __restrict__ rowsum)
{
    const int i = blockIdx.x;
    const int t = threadIdx.x;            // 0..127, 4 floats each
    const float4 a = ((const float4*)(ex + (size_t)i * 1024))[t];
    const float4 p = ((const float4*)(ex + (size_t)i * 1024 + 512))[t];
    float sa  = a.x*a.x + a.y*a.y + a.z*a.z + a.w*a.w;
    float sp  = p.x*p.x + p.y*p.y + p.z*p.z + p.w*p.w;
    float sap = a.x*p.x + a.y*p.y + a.z*p.z + a.w*p.w;
    #pragma unroll
    for (int m = 1; m < 64; m <<= 1) {
        sa  += __shfl_xor(sa,  m, 64);
        sp  += __shfl_xor(sp,  m, 64);
        sap += __shfl_xor(sap, m, 64);
    }
    __shared__ float red[3][2];
    if ((t & 63) == 0) { red[0][t>>6] = sa; red[1][t>>6] = sp; red[2][t>>6] = sap; }
    __syncthreads();
    sa  = red[0][0] + red[0][1];
    sp  = red[1][0] + red[1][1];
    sap = red[2][0] + red[2][1];
    const float inva = rsqrtf(sa);
    const float invp = rsqrtf(sp);
    ushort4 av, pv;
    av.x = f2bf(a.x * inva); av.y = f2bf(a.y * inva);
    av.z = f2bf(a.z * inva); av.w = f2bf(a.w * inva);
    pv.x = f2bf(p.x * invp); pv.y = f2bf(p.y * invp);
    pv.z = f2bf(p.z * invp); pv.w = f2bf(p.w * invp);
    ((ushort4*)(Ah + (size_t)i * DD))[t] = av;
    ((ushort4*)(Ph + (size_t)i * DD))[t] = pv;
    if (t == 0) {
        pos_sim[i] = sap * inva * invp;
        norm2[i]   = sa + sp;
        rowsum[i]  = 0.0f;
    }
}

// ---------------- GEMM 256^2, 4-slice ring, per-phase counted vmcnt ----------
__global__ __launch_bounds__(512, 2) void gemm_kernel(
    const ushort* __restrict__ Ah, const ushort* __restrict__ Ph,
    float* __restrict__ rowsum)
{
    // ls: 4 slice-slots x (A: 256x32 + B: 256x32) ushorts = 128 KiB
    __shared__ ushort ls[65536];
    const int t  = threadIdx.x;           // 0..511
    const int w  = t >> 6;                // wave 0..7
    const int l  = t & 63;
    const int wr = w >> 2, wc = w & 3;    // 2M x 4N wave grid
    const int ll = l & 15, lh = l >> 4;
    const int m0 = blockIdx.y * 256;
    const int n0 = blockIdx.x * 256;

    f32x4_t acc[8][4];
    #pragma unroll
    for (int i = 0; i < 8; i++)
        #pragma unroll
        for (int j = 0; j < 4; j++)
            acc[i][j] = (f32x4_t){0.f, 0.f, 0.f, 0.f};

    // staging: chunk = one matrix x one slice = 256 rows x 64 B = 16 KiB.
    // wave w, instr j: rows w*32+j*16..+16 -> LDS LINEAR at lane*16 (HW contract).
    // lane l -> row r = w*32+j*16+(l>>2), slot l&3; source fetches slot
    // (l&3) ^ ((r>>1)&3)  (XOR involution, verified R4).
    auto stage = [&](const ushort* src, int s, int chunkOff, int rowBase) {
        const int q = s & 3;
        #pragma unroll
        for (int j = 0; j < 2; ++j) {
            const int r   = w * 32 + j * 16 + (l >> 2);
            const int gsl = (l & 3) ^ ((r >> 1) & 3);
            const char* g = (const char*)src + (size_t)(rowBase + r) * (DD * 2)
                            + s * 64 + gsl * 16;
            __builtin_amdgcn_global_load_lds(
                (const AS1 void*)g,
                (AS3 void*)((char*)ls + q * 32768 + chunkOff
                            + w * 2048 + j * 1024 + l * 16),
                16, 0, 0);
        }
    };

    // fragment read swizzle: k-slot lh of row R at LDS slot lh ^ ((R>>1)&3),
    // (R>>1)&3 == (ll>>1)&3 (16-aligned row bases). Verified R4.
    const int sA = lh ^ ((ll >> 1) & 3);

    bf16x8_t bvk[4];     // B frags carried ph0 -> ph1

#define PH0(S, WAITSTR, DOSTAGE)                                              \
  do {                                                                        \
    const int aB = ((S) & 3) * 16384;                                         \
    const int bB = aB + 8192;                                                 \
    bf16x8_t a0[4];                                                           \
    _Pragma("unroll")                                                         \
    for (int mi = 0; mi < 4; ++mi)                                            \
      a0[mi] = *(const bf16x8_t*)&ls[aB + (wr*128 + mi*16 + ll)*32 + sA*8];   \
    _Pragma("unroll")                                                         \
    for (int ni = 0; ni < 4; ++ni)                                            \
      bvk[ni] = *(const bf16x8_t*)&ls[bB + (wc*64 + ni*16 + ll)*32 + sA*8];   \
    if (DOSTAGE) stage(Ah, (S) + 3, 0, m0);                                   \
    asm volatile("s_waitcnt vmcnt(" WAITSTR ")" ::: "memory");                \
    __builtin_amdgcn_s_setprio(1);                                            \
    _Pragma("unroll")                                                         \
    for (int mi = 0; mi < 4; ++mi)                                            \
      _Pragma("unroll")                                                       \
      for (int ni = 0; ni < 4; ++ni)                                          \
        acc[mi][ni] = __builtin_amdgcn_mfma_f32_16x16x32_bf16(                \
            a0[mi], bvk[ni], acc[mi][ni], 0, 0, 0);                           \
    __builtin_amdgcn_s_setprio(0);                                            \
    __builtin_amdgcn_s_barrier();                                             \
    __builtin_amdgcn_sched_barrier(0);                                        \
  } while (0)

#define PH1(S, WAITSTR, DOSTAGE)                                              \
  do {                                                                        \
    const int aB = ((S) & 3) * 16384;                                         \
    bf16x8_t a1[4];                                                           \
    _Pragma("unroll")                                                         \
    for (int mi = 0; mi < 4; ++mi)                                            \
      a1[mi] = *(const bf16x8_t*)&ls[aB + (wr*128 + (mi+4)*16 + ll)*32 + sA*8];\
    if (DOSTAGE) stage(Ph, (S) + 3, 16384, n0);                               \
    asm volatile("s_waitcnt vmcnt(" WAITSTR ")" ::: "memory");                \
    __builtin_amdgcn_s_setprio(1);                                            \
    _Pragma("unroll")                                                         \
    for (int mi = 0; mi < 4; ++mi)                                            \
      _Pragma("unroll")                                                       \
      for (int ni = 0; ni < 4; ++ni)                                          \
        acc[mi+4][ni] = __builtin_amdgcn_mfma_f32_16x16x32_bf16(              \
            a1[mi], bvk[ni], acc[mi+4][ni], 0, 0, 0);                         \
    __builtin_amdgcn_s_setprio(0);                                            \
    __builtin_amdgcn_s_barrier();                                             \
    __builtin_amdgcn_sched_barrier(0);                                        \
  } while (0)

    // prologue: chunks A0,B0,A1,B1,A2,B2; vmcnt(8) => slice 0 resident.
    stage(Ah, 0, 0, m0); stage(Ph, 0, 16384, n0);
    stage(Ah, 1, 0, m0); stage(Ph, 1, 16384, n0);
    stage(Ah, 2, 0, m0); stage(Ph, 2, 16384, n0);
    asm volatile("s_waitcnt vmcnt(8)" ::: "memory");
    __builtin_amdgcn_s_barrier();
    __builtin_amdgcn_sched_barrier(0);

    #pragma unroll 1
    for (int s = 0; s < 13; ++s) {
        PH0(s, "8", true);
        PH1(s, "8", true);
    }
    PH0(13, "8", false); PH1(13, "4", false);
    PH0(14, "8", false); PH1(14, "0", false);
    PH0(15, "8", false); PH1(15, "0", false);

#undef PH0
#undef PH1

    // epilogue: per-row sum of exp over this block's 256 cols -> atomicAdd.
    // C/D: col = n0 + wc*64 + ni*16 + ll ; row = m0 + wr*128 + mi*16 + lh*4 + r
    #pragma unroll
    for (int mi = 0; mi < 8; ++mi) {
        #pragma unroll
        for (int r = 0; r < 4; ++r) {
            float s = __expf(acc[mi][0][r]) + __expf(acc[mi][1][r]) +
                      __expf(acc[mi][2][r]) + __expf(acc[mi][3][r]);
            s += __shfl_xor(s, 1, 64);
            s += __shfl_xor(s, 2, 64);
            s += __shfl_xor(s, 4, 64);
            s += __shfl_xor(s, 8, 64);
            if (ll == 0)
                atomicAdd(&rowsum[m0 + wr * 128 + mi * 16 + lh * 4 + r], s);
        }
    }
}

// ---------------- final reduce (single block, fused) -------------------------
__global__ __launch_bounds__(1024) void final_kernel(
    const float* __restrict__ rowsum, const float* __restrict__ pos_sim,
    const float* __restrict__ norm2, float* __restrict__ out)
{
    const int t = threadIdx.x;
    float s1 = 0.f, s2 = 0.f;
    #pragma unroll
    for (int k = 0; k < NR / 1024; ++k) {
        const int i = k * 1024 + t;
        s1 += logf(rowsum[i] + E_CONST) - pos_sim[i];
        s2 += norm2[i];
    }
    #pragma unroll
    for (int m = 1; m < 64; m <<= 1) {
        s1 += __shfl_xor(s1, m, 64);
        s2 += __shfl_xor(s2, m, 64);
    }
    __shared__ float r1[16], r2[16];
    if ((t & 63) == 0) { r1[t >> 6] = s1; r2[t >> 6] = s2; }
    __syncthreads();
    if (t == 0) {
        float a = 0.f, b = 0.f;
        #pragma unroll
        for (int k = 0; k < 16; ++k) { a += r1[k]; b += r2[k]; }
        out[0] = a * (1.0f / NR) + 0.02f * sqrtf(b);
    }
}

extern "C" void kernel_launch(void* const* d_in, const int* in_sizes, int n_in,
                              void* d_out, int out_size, void* d_ws, size_t ws_size,
                              hipStream_t stream) {
    const float* ex = (const float*)d_in[0];
    float* out = (float*)d_out;
    char* ws = (char*)d_ws;
    ushort* Ah     = (ushort*)(ws);                         // 8 MiB
    ushort* Ph     = (ushort*)(ws + 8388608);               // 8 MiB
    float*  possim = (float*)(ws + 16777216);               // 32 KiB
    float*  norm2  = (float*)(ws + 16777216 + 32768);       // 32 KiB
    float*  rowsum = (float*)(ws + 16777216 + 65536);       // 32 KiB

    prep_kernel<<<NR, 128, 0, stream>>>(ex, Ah, Ph, possim, norm2, rowsum);
    gemm_kernel<<<dim3(NR / 256, NR / 256), 512, 0, stream>>>(Ah, Ph, rowsum);
    final_kernel<<<1, 1024, 0, stream>>>(rowsum, possim, norm2, out);
}